// Round 1
// baseline (292.097 us; speedup 1.0000x reference)
//
#include <hip/hip_runtime.h>

typedef __bf16 bf16x8 __attribute__((ext_vector_type(8)));
typedef float f32x4 __attribute__((ext_vector_type(4)));

#define MFMA16 __builtin_amdgcn_mfma_f32_16x16x32_bf16

__device__ __forceinline__ unsigned short f2bf(float f) {
  unsigned u = __float_as_uint(f);
  u += 0x7FFFu + ((u >> 16) & 1u);
  return (unsigned short)(u >> 16);
}

// ---------------- pack kernels ----------------

// posed = concat(feat[rows,512], coord[rows,3]) -> bf16 [rows, 544], zero-padded
__global__ void k_pack_posed(const float* __restrict__ feat, const float* __restrict__ coord,
                             unsigned short* __restrict__ dst, int rows) {
  int i = blockIdx.x * 256 + threadIdx.x;
  int total = rows * 544;
  if (i >= total) return;
  int r = i / 544, c = i - r * 544;
  float v = 0.f;
  if (c < 512) v = feat[(size_t)r * 512 + c];
  else if (c < 515) v = coord[(size_t)r * 3 + (c - 512)];
  dst[i] = f2bf(v);
}

// dst[n, kc] = (kc < kin) ? w[kc, n] : 0   (w is [kin, nout] row-major)
__global__ void k_pack_wT(const float* __restrict__ w, unsigned short* __restrict__ dst,
                          int kin, int nout, int kpad) {
  int i = blockIdx.x * 256 + threadIdx.x;
  if (i >= nout * kpad) return;
  int n = i / kpad, kc = i - n * kpad;
  float v = (kc < kin) ? w[(size_t)kc * nout + n] : 0.f;
  dst[i] = f2bf(v);
}

// coord head (h=8) of q/k buffer: buf[((b*9+8)*2048 + n)*64 + d] = d<3 ? coord : 0
__global__ void k_pack_ch(const float* __restrict__ coord, unsigned short* __restrict__ buf) {
  int i = blockIdx.x * 256 + threadIdx.x;
  if (i >= 4096 * 64) return;
  int row = i >> 6, d = i & 63;
  int b = row >> 11, n = row & 2047;
  float v = (d < 3) ? coord[(size_t)row * 3 + d] : 0.f;
  buf[(((size_t)b * 9 + 8) * 2048 + n) * 64 + d] = f2bf(v);
}

// ---------------- GEMM: C[m,n] = sum_k A[m,k] * BT[n,k] ----------------
// 64x64 tile, 4 waves (each wave: 16 rows x 64 cols), direct global loads.
// MODE 0: bf16 out to q/k layout  dst[((b*9+h)*2048+seq)*64+d], col=(h*64+d)
// MODE 1: bf16 out to vT layout   dst[((b*9+h)*64+d)*2048+seq]
// MODE 2: f32 out row-major       dst[m*Nout+col]
template <int MODE>
__global__ __launch_bounds__(256) void k_gemm(const unsigned short* __restrict__ A,
                                              const unsigned short* __restrict__ BT,
                                              void* __restrict__ dstv, int K, int Nout) {
  const int m0 = blockIdx.x * 64;
  const int n0 = blockIdx.y * 64;
  const int wave = threadIdx.x >> 6;
  const int lane = threadIdx.x & 63;
  const int li = lane & 15, g = lane >> 4;

  const unsigned short* ap = A + (size_t)(m0 + wave * 16 + li) * K + g * 8;
  f32x4 acc[4] = {};
  for (int k0 = 0; k0 < K; k0 += 32) {
    bf16x8 af = *(const bf16x8*)(ap + k0);
#pragma unroll
    for (int j = 0; j < 4; ++j) {
      const unsigned short* bp = BT + (size_t)(n0 + j * 16 + li) * K + k0 + g * 8;
      acc[j] = MFMA16(af, *(const bf16x8*)bp, acc[j], 0, 0, 0);
    }
  }
  const int mr = m0 + wave * 16 + 4 * g;  // + r ; D: col = li, row = 4g + r
  if constexpr (MODE == 2) {
    float* out = (float*)dstv;
#pragma unroll
    for (int j = 0; j < 4; ++j) {
      int col = n0 + j * 16 + li;
#pragma unroll
      for (int r = 0; r < 4; ++r) out[(size_t)(mr + r) * Nout + col] = acc[j][r];
    }
  } else if constexpr (MODE == 0) {
    unsigned short* out = (unsigned short*)dstv;
#pragma unroll
    for (int j = 0; j < 4; ++j) {
      int col = n0 + j * 16 + li;
      int h = col >> 6, d = col & 63;
#pragma unroll
      for (int r = 0; r < 4; ++r) {
        int m = mr + r;
        int b = m >> 11, seq = m & 2047;
        out[(((size_t)b * 9 + h) * 2048 + seq) * 64 + d] = f2bf(acc[j][r]);
      }
    }
  } else {
    unsigned short* out = (unsigned short*)dstv;
    int b = mr >> 11, seq0 = mr & 2047;  // r=0..3 are consecutive seq
#pragma unroll
    for (int j = 0; j < 4; ++j) {
      int col = n0 + j * 16 + li;
      int h = col >> 6, d = col & 63;
      ushort4 pk = make_ushort4(f2bf(acc[j][0]), f2bf(acc[j][1]), f2bf(acc[j][2]), f2bf(acc[j][3]));
      *(ushort4*)(out + (((size_t)b * 9 + h) * 64 + d) * 2048 + seq0) = pk;
    }
  }
}

// ---------------- flash attention ----------------
// grid (32, 9, 2); 4 waves/block, each wave owns 16 q-rows.
// S^T = K·Q^T  (lane holds q = lane&15, kv = kv0 + 16*t + 4g + r)
// out^T = V^T·P^T (lane holds q = lane&15, d = 16*t + 4g + r) -> stats on same lane.
__global__ __launch_bounds__(256) void k_attn(const unsigned short* __restrict__ qb,
                                              const unsigned short* __restrict__ kb,
                                              const unsigned short* __restrict__ vt,
                                              unsigned short* __restrict__ aout,
                                              const float* __restrict__ cscale) {
  __shared__ unsigned short pbuf[4][16][32];
  const int h = blockIdx.y, b = blockIdx.z;
  const int wave = threadIdx.x >> 6, lane = threadIdx.x & 63;
  const int li = lane & 15, g = lane >> 4;
  const int n0 = blockIdx.x * 64 + wave * 16;
  const size_t bh = (size_t)b * 9 + h;

  const unsigned short* qp = qb + (bh * 2048 + n0 + li) * 64 + g * 8;
  bf16x8 qf0 = *(const bf16x8*)qp;          // d = 8g+e
  bf16x8 qf1 = *(const bf16x8*)(qp + 32);   // d = 32+8g+e
  const float scale = (h == 8) ? cscale[0] : 0.125f;

  float m_run = -1e30f, l_run = 0.f;
  f32x4 acc[4] = {};
  const unsigned short* kbase = kb + bh * 2048 * 64;
  const unsigned short* vbase = vt + bh * 64 * 2048;
  unsigned short* pb = &pbuf[wave][0][0];

  for (int kv0 = 0; kv0 < 2048; kv0 += 32) {
    const unsigned short* kp0 = kbase + (size_t)(kv0 + li) * 64 + g * 8;
    f32x4 s0 = {}, s1 = {};
    s0 = MFMA16(*(const bf16x8*)kp0, qf0, s0, 0, 0, 0);
    s0 = MFMA16(*(const bf16x8*)(kp0 + 32), qf1, s0, 0, 0, 0);
    s1 = MFMA16(*(const bf16x8*)(kp0 + 1024), qf0, s1, 0, 0, 0);
    s1 = MFMA16(*(const bf16x8*)(kp0 + 1056), qf1, s1, 0, 0, 0);

    float mx = m_run;
#pragma unroll
    for (int r = 0; r < 4; ++r) {
      s0[r] *= scale;
      s1[r] *= scale;
      mx = fmaxf(mx, fmaxf(s0[r], s1[r]));
    }
    mx = fmaxf(mx, __shfl_xor(mx, 16));
    mx = fmaxf(mx, __shfl_xor(mx, 32));
    float corr = __expf(m_run - mx);
    float ts = 0.f;
    unsigned short pr0[4], pr1[4];
#pragma unroll
    for (int r = 0; r < 4; ++r) {
      float e0 = __expf(s0[r] - mx), e1 = __expf(s1[r] - mx);
      ts += e0 + e1;
      pr0[r] = f2bf(e0);
      pr1[r] = f2bf(e1);
    }
    ts += __shfl_xor(ts, 16);
    ts += __shfl_xor(ts, 32);
    l_run = l_run * corr + ts;
    m_run = mx;
#pragma unroll
    for (int t = 0; t < 4; ++t) acc[t] *= corr;

    // P round-trip through per-wave LDS: [q=li][kv_local]
    *(ushort4*)(pb + li * 32 + 4 * g) = make_ushort4(pr0[0], pr0[1], pr0[2], pr0[3]);
    *(ushort4*)(pb + li * 32 + 16 + 4 * g) = make_ushort4(pr1[0], pr1[1], pr1[2], pr1[3]);
    asm volatile("s_waitcnt lgkmcnt(0)" ::: "memory");
    __builtin_amdgcn_sched_barrier(0);
    bf16x8 pf = *(const bf16x8*)(pb + li * 32 + 8 * g);  // P[q=li][kv=8g+e]

#pragma unroll
    for (int t = 0; t < 4; ++t) {
      const unsigned short* vp = vbase + (size_t)(t * 16 + li) * 2048 + kv0 + 8 * g;
      acc[t] = MFMA16(*(const bf16x8*)vp, pf, acc[t], 0, 0, 0);
    }
  }

  float inv = 1.f / l_run;
  unsigned short* orow = aout + ((size_t)(b * 2048 + n0 + li)) * 576 + h * 64;
#pragma unroll
  for (int t = 0; t < 4; ++t) {
    ushort4 pk = make_ushort4(f2bf(acc[t][0] * inv), f2bf(acc[t][1] * inv),
                              f2bf(acc[t][2] * inv), f2bf(acc[t][3] * inv));
    *(ushort4*)(orow + t * 16 + 4 * g) = pk;  // cols h*64 + t*16 + 4g + r
  }
}

// ---------------- launch ----------------

extern "C" void kernel_launch(void* const* d_in, const int* in_sizes, int n_in,
                              void* d_out, int out_size, void* d_ws, size_t ws_size,
                              hipStream_t stream) {
  const float* x  = (const float*)d_in[0];
  const float* y  = (const float*)d_in[1];
  const float* cx = (const float*)d_in[2];
  const float* cy = (const float*)d_in[3];
  const float* Wq = (const float*)d_in[4];
  const float* Wk = (const float*)d_in[5];
  const float* Wv = (const float*)d_in[6];
  const float* Wo = (const float*)d_in[7];
  const float* cs = (const float*)d_in[8];

  char* w = (char*)d_ws;
  auto take = [&](size_t bytes) {
    char* p = w;
    w += (bytes + 255) & ~(size_t)255;
    return p;
  };
  unsigned short* posed_x = (unsigned short*)take((size_t)4096 * 544 * 2);
  unsigned short* posed_y = (unsigned short*)take((size_t)4096 * 544 * 2);
  unsigned short* wqT = (unsigned short*)take((size_t)512 * 544 * 2);
  unsigned short* wkT = (unsigned short*)take((size_t)512 * 544 * 2);
  unsigned short* wvT = (unsigned short*)take((size_t)576 * 544 * 2);
  unsigned short* woT = (unsigned short*)take((size_t)512 * 576 * 2);
  unsigned short* qbuf = (unsigned short*)take((size_t)2 * 9 * 2048 * 64 * 2);
  unsigned short* kbuf = (unsigned short*)take((size_t)2 * 9 * 2048 * 64 * 2);
  unsigned short* vtb  = (unsigned short*)take((size_t)2 * 9 * 64 * 2048 * 2);
  unsigned short* aout = (unsigned short*)take((size_t)4096 * 576 * 2);

  k_pack_posed<<<(4096 * 544 + 255) / 256, 256, 0, stream>>>(x, cx, posed_x, 4096);
  k_pack_posed<<<(4096 * 544 + 255) / 256, 256, 0, stream>>>(y, cy, posed_y, 4096);
  k_pack_wT<<<(512 * 544 + 255) / 256, 256, 0, stream>>>(Wq, wqT, 515, 512, 544);
  k_pack_wT<<<(512 * 544 + 255) / 256, 256, 0, stream>>>(Wk, wkT, 515, 512, 544);
  k_pack_wT<<<(576 * 544 + 255) / 256, 256, 0, stream>>>(Wv, wvT, 515, 576, 544);
  k_pack_wT<<<(512 * 576 + 255) / 256, 256, 0, stream>>>(Wo, woT, 576, 512, 576);
  k_pack_ch<<<(4096 * 64 + 255) / 256, 256, 0, stream>>>(cx, qbuf);
  k_pack_ch<<<(4096 * 64 + 255) / 256, 256, 0, stream>>>(cy, kbuf);

  dim3 g1(64, 8);
  k_gemm<0><<<g1, 256, 0, stream>>>(posed_x, wqT, qbuf, 544, 512);
  k_gemm<0><<<g1, 256, 0, stream>>>(posed_y, wkT, kbuf, 544, 512);
  dim3 g2(64, 9);
  k_gemm<1><<<g2, 256, 0, stream>>>(posed_y, wvT, vtb, 544, 576);

  dim3 g3(32, 9, 2);
  k_attn<<<g3, 256, 0, stream>>>(qbuf, kbuf, vtb, aout, cs);

  k_gemm<2><<<g1, 256, 0, stream>>>(aout, woT, d_out, 576, 512);
}